// Round 1
// baseline (1217.001 us; speedup 1.0000x reference)
//
#include <hip/hip_runtime.h>
#include <math.h>

#define N_NODES 200000
#define N_VAR   112000
#define N_EDGES 3200000
#define HID     64

// ---------------- kernels ----------------

// deg[dst] += 1 over edges (float accumulate; counts are small -> exact)
__global__ void k_deg(const int* __restrict__ dst, float* __restrict__ deg) {
    int e = blockIdx.x * blockDim.x + threadIdx.x;
    if (e < N_EDGES) unsafeAtomicAdd(&deg[dst[e]], 1.0f);
}

// dinv[i] = 1/sqrt(deg[i] + 1)   (in-place on the deg buffer)
__global__ void k_dinv(float* __restrict__ d) {
    int i = blockIdx.x * blockDim.x + threadIdx.x;
    if (i < N_NODES) d[i] = 1.0f / sqrtf(d[i] + 1.0f);
}

// layer-1 edge aggregation on the RAW 2-wide x:  z[dst] += x[src] * norm
__global__ void k_aggx(const int* __restrict__ src, const int* __restrict__ dst,
                       const float* __restrict__ x, const float* __restrict__ dinv,
                       float* __restrict__ z) {
    int e = blockIdx.x * blockDim.x + threadIdx.x;
    if (e < N_EDGES) {
        int s = src[e], d = dst[e];
        float n = dinv[s] * dinv[d];
        unsafeAtomicAdd(&z[2 * d],     x[2 * s]     * n);
        unsafeAtomicAdd(&z[2 * d + 1], x[2 * s + 1] * n);
    }
}

// h1 = relu( (z + x*dinv^2) @ W1 + b1 )   [node-parallel, 64 lanes = 64 features]
__global__ void __launch_bounds__(256) k_h1(const float* __restrict__ x,
                                            const float* __restrict__ z,
                                            const float* __restrict__ dinv,
                                            const float* __restrict__ W1,
                                            const float* __restrict__ b1,
                                            float* __restrict__ h1) {
    int v = blockIdx.x * 4 + (threadIdx.x >> 6);
    int f = threadIdx.x & 63;
    if (v >= N_NODES) return;
    float di = dinv[v];
    float sl = di * di;
    float z0 = z[2 * v]     + x[2 * v]     * sl;
    float z1 = z[2 * v + 1] + x[2 * v + 1] * sl;
    float h = fmaf(z0, W1[f], fmaf(z1, W1[64 + f], b1[f]));
    h1[(long long)v * 64 + f] = fmaxf(h, 0.0f);
}

// layer-2 edge aggregation on h1 (64-wide). One wave per edge, lane = feature.
// Only dst < N_VAR matter for the final output -> skip the rest (wave-uniform).
__global__ void __launch_bounds__(256) k_aggh(const int* __restrict__ src,
                                              const int* __restrict__ dst,
                                              const float* __restrict__ h1,
                                              const float* __restrict__ dinv,
                                              float* __restrict__ a1) {
    int gid = blockIdx.x * 256 + threadIdx.x;   // max 204.8M < 2^31
    int e = gid >> 6;
    int f = gid & 63;
    if (e >= N_EDGES) return;
    int d = dst[e];
    if (d >= N_VAR) return;                      // uniform across the wave
    int s = src[e];
    float n = dinv[s] * dinv[d];
    unsafeAtomicAdd(&a1[(long long)d * 64 + f], h1[(long long)s * 64 + f] * n);
}

// epilogue for var nodes: A = a1 + h1*dinv^2 ; t = A@W2+b2 ; o = relu(t@Wfc+bfc); round
__global__ void __launch_bounds__(256) k_out(const float* __restrict__ a1,
                                             const float* __restrict__ h1,
                                             const float* __restrict__ dinv,
                                             const float* __restrict__ W2,
                                             const float* __restrict__ b2,
                                             const float* __restrict__ Wfc,
                                             const float* __restrict__ bfc,
                                             float* __restrict__ out) {
    __shared__ float A[4][64];
    __shared__ float T[4][64];
    int w = threadIdx.x >> 6;
    int l = threadIdx.x & 63;
    int v = blockIdx.x * 4 + w;
    bool ok = (v < N_VAR);
    if (ok) {
        float di = dinv[v];
        A[w][l] = a1[(long long)v * 64 + l] + h1[(long long)v * 64 + l] * (di * di);
    }
    __syncthreads();
    if (ok) {
        float acc = b2[l];
        #pragma unroll
        for (int j = 0; j < 64; ++j)
            acc = fmaf(A[w][j], W2[j * 64 + l], acc);
        T[w][l] = acc;
    }
    __syncthreads();
    if (ok) {
        float o = bfc[l];
        #pragma unroll
        for (int k = 0; k < 64; ++k)
            o = fmaf(T[w][k], Wfc[k * 64 + l], o);
        o = fmaxf(o, 0.0f);
        out[(long long)v * 64 + l] = rintf(o);   // round-half-even, matches jnp.round
    }
}

// ---------------- launch ----------------

extern "C" void kernel_launch(void* const* d_in, const int* in_sizes, int n_in,
                              void* d_out, int out_size, void* d_ws, size_t ws_size,
                              hipStream_t stream) {
    const float* x    = (const float*)d_in[0];
    const int*   ei   = (const int*)  d_in[1];
    const float* W1   = (const float*)d_in[2];
    const float* b1   = (const float*)d_in[3];
    const float* W2   = (const float*)d_in[4];
    const float* b2   = (const float*)d_in[5];
    const float* Wfc  = (const float*)d_in[6];
    const float* bfc  = (const float*)d_in[7];
    float* out = (float*)d_out;

    const int* src = ei;            // edge_index[0]
    const int* dst = ei + N_EDGES;  // edge_index[1]

    // workspace layout (bytes)
    char* ws = (char*)d_ws;
    float* dinv = (float*)(ws);                         // N_NODES floats (deg then dinv)
    float* z    = (float*)(ws + 800000);                // N_NODES*2 floats
    float* h1   = (float*)(ws + 2400000);               // N_NODES*64 floats
    float* a1   = (float*)(ws + 53600000);              // N_VAR*64 floats
    // total: 53,600,000 + 28,672,000 = 82,272,000 bytes

    hipMemsetAsync(dinv, 0, (size_t)N_NODES * 4, stream);
    hipMemsetAsync(z,    0, (size_t)N_NODES * 2 * 4, stream);
    hipMemsetAsync(a1,   0, (size_t)N_VAR * 64 * 4, stream);

    int eb = (N_EDGES + 255) / 256;
    k_deg<<<eb, 256, 0, stream>>>(dst, dinv);
    k_dinv<<<(N_NODES + 255) / 256, 256, 0, stream>>>(dinv);
    k_aggx<<<eb, 256, 0, stream>>>(src, dst, x, dinv, z);
    k_h1<<<(N_NODES + 3) / 4, 256, 0, stream>>>(x, z, dinv, W1, b1, h1);

    long long tot = (long long)N_EDGES * 64;
    int ab = (int)((tot + 255) / 256);
    k_aggh<<<ab, 256, 0, stream>>>(src, dst, h1, dinv, a1);

    k_out<<<(N_VAR + 3) / 4, 256, 0, stream>>>(a1, h1, dinv, W2, b2, Wfc, bfc, out);
}

// Round 2
// 901.400 us; speedup vs baseline: 1.3501x; 1.3501x over previous
//
#include <hip/hip_runtime.h>
#include <math.h>

#define N_NODES 200000
#define N_VAR   112000
#define N_EDGES 3200000
#define NB_SCAN 782           // ceil(200000/256)

// ---------- CSR build ----------

__global__ void k_count(const int* __restrict__ dst, int* __restrict__ deg) {
    int e = blockIdx.x * blockDim.x + threadIdx.x;
    if (e < N_EDGES) atomicAdd(&deg[dst[e]], 1);
}

// block-local exclusive scan of deg -> rp (local), block sums -> bsum
__global__ void __launch_bounds__(256) k_scan1(const int* __restrict__ deg,
                                               int* __restrict__ rp,
                                               int* __restrict__ bsum) {
    __shared__ int tmp[256];
    int i = blockIdx.x * 256 + threadIdx.x;
    int v = (i < N_NODES) ? deg[i] : 0;
    tmp[threadIdx.x] = v;
    __syncthreads();
    for (int off = 1; off < 256; off <<= 1) {
        int t = (threadIdx.x >= off) ? tmp[threadIdx.x - off] : 0;
        __syncthreads();
        tmp[threadIdx.x] += t;
        __syncthreads();
    }
    if (i < N_NODES) rp[i] = tmp[threadIdx.x] - v;   // exclusive
    if (threadIdx.x == 255) bsum[blockIdx.x] = tmp[255];
}

// exclusive scan of the 782 block sums, single block of 1024
__global__ void __launch_bounds__(1024) k_scan2(int* __restrict__ bsum) {
    __shared__ int tmp[1024];
    int v = (threadIdx.x < NB_SCAN) ? bsum[threadIdx.x] : 0;
    tmp[threadIdx.x] = v;
    __syncthreads();
    for (int off = 1; off < 1024; off <<= 1) {
        int t = (threadIdx.x >= off) ? tmp[threadIdx.x - off] : 0;
        __syncthreads();
        tmp[threadIdx.x] += t;
        __syncthreads();
    }
    if (threadIdx.x < NB_SCAN) bsum[threadIdx.x] = tmp[threadIdx.x] - v;
}

// finalize row_ptr (in place), init cursor, compute dinv and xn = x*dinv
__global__ void __launch_bounds__(256) k_scan3(const int* __restrict__ deg,
                                               int* __restrict__ rp,
                                               const int* __restrict__ bsum,
                                               int* __restrict__ cursor,
                                               const float* __restrict__ x,
                                               float* __restrict__ dinv,
                                               float2* __restrict__ xn) {
    int i = blockIdx.x * 256 + threadIdx.x;
    if (i >= N_NODES) return;
    int r = rp[i] + bsum[blockIdx.x];
    rp[i] = r;
    cursor[i] = r;
    float dv = rsqrtf((float)deg[i] + 1.0f);
    dinv[i] = dv;
    float2 xv = ((const float2*)x)[i];
    xn[i] = make_float2(xv.x * dv, xv.y * dv);
}

__global__ void k_scatter(const int* __restrict__ src, const int* __restrict__ dst,
                          int* __restrict__ cursor, int* __restrict__ csr) {
    int e = blockIdx.x * blockDim.x + threadIdx.x;
    if (e < N_EDGES) {
        int pos = atomicAdd(&cursor[dst[e]], 1);
        csr[pos] = src[e];
    }
}

// ---------- layer 1: g[v] = relu( (dinv_v*(sum xn[s] + xn[v])) @ W1 + b1 ) * dinv_v ----------
// one wave per node; lanes fetch up to 64 srcs coalesced, then shfl-broadcast.
__global__ void __launch_bounds__(256) k_l1(const int* __restrict__ rp,
                                            const int* __restrict__ deg,
                                            const int* __restrict__ csr,
                                            const float2* __restrict__ xn,
                                            const float* __restrict__ dinv,
                                            const float* __restrict__ W1,
                                            const float* __restrict__ b1,
                                            float* __restrict__ g) {
    int w = threadIdx.x >> 6, l = threadIdx.x & 63;
    int v = blockIdx.x * 4 + w;
    if (v >= N_NODES) return;
    int beg = rp[v], n = deg[v];
    float2 self = xn[v];
    float z0 = self.x, z1 = self.y;
    for (int base = 0; base < n; base += 64) {
        int cnt = n - base; if (cnt > 64) cnt = 64;
        int sv = (l < cnt) ? csr[beg + base + l] : 0;
        for (int j = 0; j < cnt; ++j) {
            int s = __shfl(sv, j);
            float2 xs = xn[s];          // broadcast load (same addr all lanes)
            z0 += xs.x; z1 += xs.y;
        }
    }
    float dv = dinv[v];
    z0 *= dv; z1 *= dv;
    float h = fmaf(z0, W1[l], fmaf(z1, W1[64 + l], b1[l]));
    g[(long long)v * 64 + l] = fmaxf(h, 0.0f) * dv;
}

// ---------- layer 2 + fc, var nodes only ----------
// acc = dinv_v * (sum_{s in N(v)} g[s] + g[v]);  t = acc@W2+b2;  out = rint(relu(t@Wfc+bfc))
__global__ void __launch_bounds__(256) k_l2(const int* __restrict__ rp,
                                            const int* __restrict__ deg,
                                            const int* __restrict__ csr,
                                            const float* __restrict__ g,
                                            const float* __restrict__ dinv,
                                            const float* __restrict__ W2,
                                            const float* __restrict__ b2,
                                            const float* __restrict__ Wfc,
                                            const float* __restrict__ bfc,
                                            float* __restrict__ out) {
    __shared__ float A[4][64];
    __shared__ float T[4][64];
    int w = threadIdx.x >> 6, l = threadIdx.x & 63;
    int v = blockIdx.x * 4 + w;        // grid = N_VAR/4 exactly; v < N_VAR always
    int beg = rp[v], n = deg[v];
    float acc = g[(long long)v * 64 + l];          // self loop
    for (int base = 0; base < n; base += 64) {
        int cnt = n - base; if (cnt > 64) cnt = 64;
        int sv = (l < cnt) ? csr[beg + base + l] : 0;
        for (int j = 0; j < cnt; ++j) {
            int s = __shfl(sv, j);
            acc += g[(long long)s * 64 + l];       // coalesced 256B row gather
        }
    }
    A[w][l] = acc * dinv[v];
    __syncthreads();
    float t = b2[l];
    #pragma unroll
    for (int j = 0; j < 64; ++j)
        t = fmaf(A[w][j], W2[j * 64 + l], t);
    T[w][l] = t;
    __syncthreads();
    float o = bfc[l];
    #pragma unroll
    for (int k = 0; k < 64; ++k)
        o = fmaf(T[w][k], Wfc[k * 64 + l], o);
    out[(long long)v * 64 + l] = rintf(fmaxf(o, 0.0f));
}

// ---------------- launch ----------------

extern "C" void kernel_launch(void* const* d_in, const int* in_sizes, int n_in,
                              void* d_out, int out_size, void* d_ws, size_t ws_size,
                              hipStream_t stream) {
    const float* x    = (const float*)d_in[0];
    const int*   ei   = (const int*)  d_in[1];
    const float* W1   = (const float*)d_in[2];
    const float* b1   = (const float*)d_in[3];
    const float* W2   = (const float*)d_in[4];
    const float* b2   = (const float*)d_in[5];
    const float* Wfc  = (const float*)d_in[6];
    const float* bfc  = (const float*)d_in[7];
    float* out = (float*)d_out;

    const int* src = ei;
    const int* dst = ei + N_EDGES;

    // workspace layout (bytes), all 16-aligned
    char* ws = (char*)d_ws;
    int*    deg    = (int*)   (ws + 0);          //   800,000
    int*    rp     = (int*)   (ws + 800000);     //   800,000
    int*    cursor = (int*)   (ws + 1600000);    //   800,000
    int*    bsum   = (int*)   (ws + 2400000);    //     4,096
    float*  dinv   = (float*) (ws + 2404096);    //   800,000
    float2* xn     = (float2*)(ws + 3204096);    // 1,600,000
    int*    csr    = (int*)   (ws + 4804096);    // 12,800,000
    float*  g      = (float*) (ws + 17604096);   // 51,200,000  -> total 68.8 MB

    hipMemsetAsync(deg, 0, (size_t)N_NODES * 4, stream);

    int eb = (N_EDGES + 255) / 256;
    k_count  <<<eb, 256, 0, stream>>>(dst, deg);
    k_scan1  <<<NB_SCAN, 256, 0, stream>>>(deg, rp, bsum);
    k_scan2  <<<1, 1024, 0, stream>>>(bsum);
    k_scan3  <<<NB_SCAN, 256, 0, stream>>>(deg, rp, bsum, cursor, x, dinv, xn);
    k_scatter<<<eb, 256, 0, stream>>>(src, dst, cursor, csr);

    k_l1<<<(N_NODES + 3) / 4, 256, 0, stream>>>(rp, deg, csr, xn, dinv, W1, b1, g);
    k_l2<<<N_VAR / 4, 256, 0, stream>>>(rp, deg, csr, g, dinv, W2, b2, Wfc, bfc, out);
}

// Round 4
// 711.882 us; speedup vs baseline: 1.7096x; 1.2662x over previous
//
#include <hip/hip_runtime.h>
#include <math.h>

#define N_NODES 200000
#define N_VAR   112000
#define N_EDGES 3200000
#define NB_SCAN 782           // ceil(200000/256)

// ---------- CSR build ----------

__global__ void k_count(const int* __restrict__ dst, int* __restrict__ deg) {
    int e = blockIdx.x * blockDim.x + threadIdx.x;
    if (e < N_EDGES) atomicAdd(&deg[dst[e]], 1);
}

__global__ void __launch_bounds__(256) k_scan1(const int* __restrict__ deg,
                                               int* __restrict__ rp,
                                               int* __restrict__ bsum) {
    __shared__ int tmp[256];
    int i = blockIdx.x * 256 + threadIdx.x;
    int v = (i < N_NODES) ? deg[i] : 0;
    tmp[threadIdx.x] = v;
    __syncthreads();
    for (int off = 1; off < 256; off <<= 1) {
        int t = (threadIdx.x >= off) ? tmp[threadIdx.x - off] : 0;
        __syncthreads();
        tmp[threadIdx.x] += t;
        __syncthreads();
    }
    if (i < N_NODES) rp[i] = tmp[threadIdx.x] - v;   // exclusive
    if (threadIdx.x == 255) bsum[blockIdx.x] = tmp[255];
}

__global__ void __launch_bounds__(1024) k_scan2(int* __restrict__ bsum) {
    __shared__ int tmp[1024];
    int v = (threadIdx.x < NB_SCAN) ? bsum[threadIdx.x] : 0;
    tmp[threadIdx.x] = v;
    __syncthreads();
    for (int off = 1; off < 1024; off <<= 1) {
        int t = (threadIdx.x >= off) ? tmp[threadIdx.x - off] : 0;
        __syncthreads();
        tmp[threadIdx.x] += t;
        __syncthreads();
    }
    if (threadIdx.x < NB_SCAN) bsum[threadIdx.x] = tmp[threadIdx.x] - v;
}

// finalize row_ptr, init cursor, compute dinv and xn = x*dinv
__global__ void __launch_bounds__(256) k_scan3(const int* __restrict__ deg,
                                               int* __restrict__ rp,
                                               const int* __restrict__ bsum,
                                               int* __restrict__ cursor,
                                               const float* __restrict__ x,
                                               float* __restrict__ dinv,
                                               float2* __restrict__ xn) {
    int i = blockIdx.x * 256 + threadIdx.x;
    if (i >= N_NODES) return;
    int r = rp[i] + bsum[blockIdx.x];
    rp[i] = r;
    cursor[i] = r;
    float dv = rsqrtf((float)deg[i] + 1.0f);
    dinv[i] = dv;
    float2 xv = ((const float2*)x)[i];
    xn[i] = make_float2(xv.x * dv, xv.y * dv);
}

__global__ void k_scatter(const int* __restrict__ src, const int* __restrict__ dst,
                          int* __restrict__ cursor, int* __restrict__ csr) {
    int e = blockIdx.x * blockDim.x + threadIdx.x;
    if (e < N_EDGES) {
        int pos = atomicAdd(&cursor[dst[e]], 1);
        csr[pos] = src[e];
    }
}

// ---------- layer 1a: z[v] = xn[v] + sum_{s in N(v)} xn[s]  (CSR order, single chain) ----------
// Loads batched 4-wide for MLP; adds kept in round-2 bit-exact order (self first, then CSR).
__global__ void __launch_bounds__(256) k_l1a(const int* __restrict__ rp,
                                             const int* __restrict__ deg,
                                             const int* __restrict__ csr,
                                             const float2* __restrict__ xn,
                                             float2* __restrict__ z) {
    int v = blockIdx.x * 256 + threadIdx.x;
    if (v >= N_NODES) return;
    int beg = rp[v], n = deg[v];
    float2 self = xn[v];
    float zx = self.x, zy = self.y;          // self FIRST (round-2 order)
    int j = 0;
    for (; j + 4 <= n; j += 4) {
        int s0 = csr[beg + j],     s1 = csr[beg + j + 1];
        int s2 = csr[beg + j + 2], s3 = csr[beg + j + 3];
        float2 p0 = xn[s0], p1 = xn[s1], p2 = xn[s2], p3 = xn[s3];
        zx += p0.x; zy += p0.y;              // sequential chain, CSR order
        zx += p1.x; zy += p1.y;
        zx += p2.x; zy += p2.y;
        zx += p3.x; zy += p3.y;
    }
    for (; j < n; ++j) {
        int s = csr[beg + j];
        float2 p = xn[s];
        zx += p.x; zy += p.y;
    }
    z[v] = make_float2(zx, zy);
}

// ---------- layer 1b: g[v] = relu( (z[v]*dinv) @ W1 + b1 ) * dinv  (z already includes self) ----------
__global__ void __launch_bounds__(256) k_l1b(const float2* __restrict__ z,
                                             const float* __restrict__ dinv,
                                             const float* __restrict__ W1,
                                             const float* __restrict__ b1,
                                             float* __restrict__ g) {
    int gid = blockIdx.x * 256 + threadIdx.x;
    int v = gid >> 6, l = gid & 63;
    if (v >= N_NODES) return;
    float dv = dinv[v];
    float2 zv = z[v];
    float i0 = zv.x * dv;
    float i1 = zv.y * dv;
    float h = fmaf(i0, W1[l], fmaf(i1, W1[64 + l], b1[l]));
    g[(long long)v * 64 + l] = fmaxf(h, 0.0f) * dv;
}

// ---------- layer 2 + fc, var nodes only ----------
// Single accumulator chain in CSR order (bit-exact vs round 2); loads batched 4-wide.
__global__ void __launch_bounds__(256) k_l2(const int* __restrict__ rp,
                                            const int* __restrict__ deg,
                                            const int* __restrict__ csr,
                                            const float* __restrict__ g,
                                            const float* __restrict__ dinv,
                                            const float* __restrict__ W2,
                                            const float* __restrict__ b2,
                                            const float* __restrict__ Wfc,
                                            const float* __restrict__ bfc,
                                            float* __restrict__ out) {
    __shared__ float A[4][64];
    __shared__ float T[4][64];
    int w = threadIdx.x >> 6, l = threadIdx.x & 63;
    int v = blockIdx.x * 4 + w;        // grid = N_VAR/4 exactly
    int beg = rp[v], n = deg[v];
    float acc = g[(long long)v * 64 + l];   // self loop first (round-2 order)
    for (int base = 0; base < n; base += 64) {
        int cnt = n - base; if (cnt > 64) cnt = 64;
        int sv = (l < cnt) ? csr[beg + base + l] : 0;
        int j = 0;
        for (; j + 4 <= cnt; j += 4) {
            int s0 = __shfl(sv, j),     s1 = __shfl(sv, j + 1);
            int s2 = __shfl(sv, j + 2), s3 = __shfl(sv, j + 3);
            float r0 = g[(long long)s0 * 64 + l];
            float r1 = g[(long long)s1 * 64 + l];
            float r2 = g[(long long)s2 * 64 + l];
            float r3 = g[(long long)s3 * 64 + l];
            acc += r0; acc += r1; acc += r2; acc += r3;   // CSR-order chain
        }
        for (; j < cnt; ++j) {
            int s = __shfl(sv, j);
            acc += g[(long long)s * 64 + l];
        }
    }
    A[w][l] = acc * dinv[v];
    __syncthreads();
    float t = b2[l];
    #pragma unroll
    for (int j = 0; j < 64; ++j)
        t = fmaf(A[w][j], W2[j * 64 + l], t);
    T[w][l] = t;
    __syncthreads();
    float o = bfc[l];
    #pragma unroll
    for (int k = 0; k < 64; ++k)
        o = fmaf(T[w][k], Wfc[k * 64 + l], o);
    out[(long long)v * 64 + l] = rintf(fmaxf(o, 0.0f));
}

// ---------------- launch ----------------

extern "C" void kernel_launch(void* const* d_in, const int* in_sizes, int n_in,
                              void* d_out, int out_size, void* d_ws, size_t ws_size,
                              hipStream_t stream) {
    const float* x    = (const float*)d_in[0];
    const int*   ei   = (const int*)  d_in[1];
    const float* W1   = (const float*)d_in[2];
    const float* b1   = (const float*)d_in[3];
    const float* W2   = (const float*)d_in[4];
    const float* b2   = (const float*)d_in[5];
    const float* Wfc  = (const float*)d_in[6];
    const float* bfc  = (const float*)d_in[7];
    float* out = (float*)d_out;

    const int* src = ei;
    const int* dst = ei + N_EDGES;

    // workspace layout (bytes), 16-aligned
    char* ws = (char*)d_ws;
    int*    deg    = (int*)   (ws + 0);          //   800,000
    int*    rp     = (int*)   (ws + 800000);     //   800,000
    int*    cursor = (int*)   (ws + 1600000);    //   800,000
    int*    bsum   = (int*)   (ws + 2400000);    //     4,096
    float*  dinv   = (float*) (ws + 2404096);    //   800,000
    float2* xn     = (float2*)(ws + 3204096);    // 1,600,000
    float2* z      = (float2*)(ws + 4804096);    // 1,600,000
    int*    csr    = (int*)   (ws + 6404096);    // 12,800,000
    float*  g      = (float*) (ws + 19204096);   // 51,200,000 -> total 70.4 MB

    hipMemsetAsync(deg, 0, (size_t)N_NODES * 4, stream);

    int eb = (N_EDGES + 255) / 256;
    k_count  <<<eb, 256, 0, stream>>>(dst, deg);
    k_scan1  <<<NB_SCAN, 256, 0, stream>>>(deg, rp, bsum);
    k_scan2  <<<1, 1024, 0, stream>>>(bsum);
    k_scan3  <<<NB_SCAN, 256, 0, stream>>>(deg, rp, bsum, cursor, x, dinv, xn);
    k_scatter<<<eb, 256, 0, stream>>>(src, dst, cursor, csr);

    k_l1a<<<NB_SCAN, 256, 0, stream>>>(rp, deg, csr, xn, z);
    k_l1b<<<(N_NODES * 64 + 255) / 256, 256, 0, stream>>>(z, dinv, W1, b1, g);
    k_l2 <<<N_VAR / 4, 256, 0, stream>>>(rp, deg, csr, g, dinv, W2, b2, Wfc, bfc, out);
}

// Round 5
// 591.359 us; speedup vs baseline: 2.0580x; 1.2038x over previous
//
#include <hip/hip_runtime.h>
#include <math.h>

#define N_NODES 200000
#define N_VAR   112000
#define N_EDGES 3200000
#define NB_SCAN 782           // ceil(200000/256)
#define PART_SZ 25000         // N_NODES / 8 partitions (one per XCD)
#define SC_CHUNK 2048         // edges scanned per scatter block
#define SC_NCHUNK 1563        // ceil(N_EDGES / SC_CHUNK)

// ---------- CSR build ----------

__global__ void k_count(const int* __restrict__ dst, int* __restrict__ deg) {
    int e = blockIdx.x * blockDim.x + threadIdx.x;
    if (e < N_EDGES) atomicAdd(&deg[dst[e]], 1);
}

__global__ void __launch_bounds__(256) k_scan1(const int* __restrict__ deg,
                                               int* __restrict__ rp,
                                               int* __restrict__ bsum) {
    __shared__ int tmp[256];
    int i = blockIdx.x * 256 + threadIdx.x;
    int v = (i < N_NODES) ? deg[i] : 0;
    tmp[threadIdx.x] = v;
    __syncthreads();
    for (int off = 1; off < 256; off <<= 1) {
        int t = (threadIdx.x >= off) ? tmp[threadIdx.x - off] : 0;
        __syncthreads();
        tmp[threadIdx.x] += t;
        __syncthreads();
    }
    if (i < N_NODES) rp[i] = tmp[threadIdx.x] - v;   // exclusive
    if (threadIdx.x == 255) bsum[blockIdx.x] = tmp[255];
}

__global__ void __launch_bounds__(1024) k_scan2(int* __restrict__ bsum) {
    __shared__ int tmp[1024];
    int v = (threadIdx.x < NB_SCAN) ? bsum[threadIdx.x] : 0;
    tmp[threadIdx.x] = v;
    __syncthreads();
    for (int off = 1; off < 1024; off <<= 1) {
        int t = (threadIdx.x >= off) ? tmp[threadIdx.x - off] : 0;
        __syncthreads();
        tmp[threadIdx.x] += t;
        __syncthreads();
    }
    if (threadIdx.x < NB_SCAN) bsum[threadIdx.x] = tmp[threadIdx.x] - v;
}

// finalize row_ptr, init cursor, compute dinv and xn = x*dinv
__global__ void __launch_bounds__(256) k_scan3(const int* __restrict__ deg,
                                               int* __restrict__ rp,
                                               const int* __restrict__ bsum,
                                               int* __restrict__ cursor,
                                               const float* __restrict__ x,
                                               float* __restrict__ dinv,
                                               float2* __restrict__ xn) {
    int i = blockIdx.x * 256 + threadIdx.x;
    if (i >= N_NODES) return;
    int r = rp[i] + bsum[blockIdx.x];
    rp[i] = r;
    cursor[i] = r;
    float dv = rsqrtf((float)deg[i] + 1.0f);
    dinv[i] = dv;
    float2 xv = ((const float2*)x)[i];
    xn[i] = make_float2(xv.x * dv, xv.y * dv);
}

// XCD-partitioned scatter: block b owns dst range [ (b&7)*PART_SZ, +PART_SZ ).
// blockIdx%8 round-robins onto the 8 XCDs, so each partition's 1.6MB CSR span
// is written by (mostly) one XCD's L2 -> dirty lines fill before eviction.
__global__ void __launch_bounds__(256) k_scatter(const int* __restrict__ src,
                                                 const int* __restrict__ dst,
                                                 int* __restrict__ cursor,
                                                 int* __restrict__ csr) {
    int part  = blockIdx.x & 7;
    int chunk = blockIdx.x >> 3;
    int lo = part * PART_SZ, hi = lo + PART_SZ;
    int base = chunk * SC_CHUNK;
    #pragma unroll
    for (int i = 0; i < SC_CHUNK / 256; ++i) {
        int e = base + i * 256 + threadIdx.x;
        if (e < N_EDGES) {
            int d = dst[e];
            if (d >= lo && d < hi) {
                int pos = atomicAdd(&cursor[d], 1);
                csr[pos] = src[e];
            }
        }
    }
}

// ---------- layer 1a: z[v] = xn[v] + sum_{s in N(v)} xn[s]  (fp64 acc, ILP-8) ----------
__global__ void __launch_bounds__(256) k_l1a(const int* __restrict__ rp,
                                             const int* __restrict__ deg,
                                             const int* __restrict__ csr,
                                             const float2* __restrict__ xn,
                                             float2* __restrict__ z) {
    int v = blockIdx.x * 256 + threadIdx.x;
    if (v >= N_NODES) return;
    int beg = rp[v], n = deg[v];
    float2 self = xn[v];
    double ax = self.x, ay = self.y;
    double bx = 0.0,    by = 0.0;
    int j = 0;
    for (; j + 8 <= n; j += 8) {
        int s0 = csr[beg + j],     s1 = csr[beg + j + 1];
        int s2 = csr[beg + j + 2], s3 = csr[beg + j + 3];
        int s4 = csr[beg + j + 4], s5 = csr[beg + j + 5];
        int s6 = csr[beg + j + 6], s7 = csr[beg + j + 7];
        float2 p0 = xn[s0], p1 = xn[s1], p2 = xn[s2], p3 = xn[s3];
        float2 p4 = xn[s4], p5 = xn[s5], p6 = xn[s6], p7 = xn[s7];
        ax += p0.x; ay += p0.y;  bx += p1.x; by += p1.y;
        ax += p2.x; ay += p2.y;  bx += p3.x; by += p3.y;
        ax += p4.x; ay += p4.y;  bx += p5.x; by += p5.y;
        ax += p6.x; ay += p6.y;  bx += p7.x; by += p7.y;
    }
    for (; j < n; ++j) {
        int s = csr[beg + j];
        float2 p = xn[s];
        ax += p.x; ay += p.y;
    }
    z[v] = make_float2((float)(ax + bx), (float)(ay + by));
}

// ---------- layer 1b: g[v] = relu( (z[v]*dinv) @ W1 + b1 ) * dinv ----------
__global__ void __launch_bounds__(256) k_l1b(const float2* __restrict__ z,
                                             const float* __restrict__ dinv,
                                             const float* __restrict__ W1,
                                             const float* __restrict__ b1,
                                             float* __restrict__ g) {
    int gid = blockIdx.x * 256 + threadIdx.x;
    int v = gid >> 6, l = gid & 63;
    if (v >= N_NODES) return;
    float dv = dinv[v];
    float2 zv = z[v];
    float i0 = zv.x * dv;
    float i1 = zv.y * dv;
    float h = fmaf(i0, W1[l], fmaf(i1, W1[64 + l], b1[l]));
    g[(long long)v * 64 + l] = fmaxf(h, 0.0f) * dv;
}

// ---------- layer 2 + fc, var nodes only (fp64 acc, ILP-8) ----------
__global__ void __launch_bounds__(256) k_l2(const int* __restrict__ rp,
                                            const int* __restrict__ deg,
                                            const int* __restrict__ csr,
                                            const float* __restrict__ g,
                                            const float* __restrict__ dinv,
                                            const float* __restrict__ W2,
                                            const float* __restrict__ b2,
                                            const float* __restrict__ Wfc,
                                            const float* __restrict__ bfc,
                                            float* __restrict__ out) {
    __shared__ float A[4][64];
    __shared__ float T[4][64];
    int w = threadIdx.x >> 6, l = threadIdx.x & 63;
    int v = blockIdx.x * 4 + w;        // grid = N_VAR/4 exactly
    int beg = rp[v], n = deg[v];
    double acc0 = g[(long long)v * 64 + l];   // self loop
    double acc1 = 0.0;
    for (int base = 0; base < n; base += 64) {
        int cnt = n - base; if (cnt > 64) cnt = 64;
        int sv = (l < cnt) ? csr[beg + base + l] : 0;
        int j = 0;
        for (; j + 8 <= cnt; j += 8) {
            int s0 = __shfl(sv, j),     s1 = __shfl(sv, j + 1);
            int s2 = __shfl(sv, j + 2), s3 = __shfl(sv, j + 3);
            int s4 = __shfl(sv, j + 4), s5 = __shfl(sv, j + 5);
            int s6 = __shfl(sv, j + 6), s7 = __shfl(sv, j + 7);
            float r0 = g[(long long)s0 * 64 + l];
            float r1 = g[(long long)s1 * 64 + l];
            float r2 = g[(long long)s2 * 64 + l];
            float r3 = g[(long long)s3 * 64 + l];
            float r4 = g[(long long)s4 * 64 + l];
            float r5 = g[(long long)s5 * 64 + l];
            float r6 = g[(long long)s6 * 64 + l];
            float r7 = g[(long long)s7 * 64 + l];
            acc0 += r0; acc1 += r1; acc0 += r2; acc1 += r3;
            acc0 += r4; acc1 += r5; acc0 += r6; acc1 += r7;
        }
        for (; j < cnt; ++j) {
            int s = __shfl(sv, j);
            acc0 += g[(long long)s * 64 + l];
        }
    }
    A[w][l] = (float)(acc0 + acc1) * dinv[v];
    __syncthreads();
    float t = b2[l];
    #pragma unroll
    for (int j = 0; j < 64; ++j)
        t = fmaf(A[w][j], W2[j * 64 + l], t);
    T[w][l] = t;
    __syncthreads();
    float o = bfc[l];
    #pragma unroll
    for (int k = 0; k < 64; ++k)
        o = fmaf(T[w][k], Wfc[k * 64 + l], o);
    out[(long long)v * 64 + l] = rintf(fmaxf(o, 0.0f));
}

// ---------------- launch ----------------

extern "C" void kernel_launch(void* const* d_in, const int* in_sizes, int n_in,
                              void* d_out, int out_size, void* d_ws, size_t ws_size,
                              hipStream_t stream) {
    const float* x    = (const float*)d_in[0];
    const int*   ei   = (const int*)  d_in[1];
    const float* W1   = (const float*)d_in[2];
    const float* b1   = (const float*)d_in[3];
    const float* W2   = (const float*)d_in[4];
    const float* b2   = (const float*)d_in[5];
    const float* Wfc  = (const float*)d_in[6];
    const float* bfc  = (const float*)d_in[7];
    float* out = (float*)d_out;

    const int* src = ei;
    const int* dst = ei + N_EDGES;

    // workspace layout (bytes), 16-aligned
    char* ws = (char*)d_ws;
    int*    deg    = (int*)   (ws + 0);          //   800,000
    int*    rp     = (int*)   (ws + 800000);     //   800,000
    int*    cursor = (int*)   (ws + 1600000);    //   800,000
    int*    bsum   = (int*)   (ws + 2400000);    //     4,096
    float*  dinv   = (float*) (ws + 2404096);    //   800,000
    float2* xn     = (float2*)(ws + 3204096);    // 1,600,000
    float2* z      = (float2*)(ws + 4804096);    // 1,600,000
    int*    csr    = (int*)   (ws + 6404096);    // 12,800,000
    float*  g      = (float*) (ws + 19204096);   // 51,200,000 -> total 70.4 MB

    hipMemsetAsync(deg, 0, (size_t)N_NODES * 4, stream);

    int eb = (N_EDGES + 255) / 256;
    k_count  <<<eb, 256, 0, stream>>>(dst, deg);
    k_scan1  <<<NB_SCAN, 256, 0, stream>>>(deg, rp, bsum);
    k_scan2  <<<1, 1024, 0, stream>>>(bsum);
    k_scan3  <<<NB_SCAN, 256, 0, stream>>>(deg, rp, bsum, cursor, x, dinv, xn);
    k_scatter<<<8 * SC_NCHUNK, 256, 0, stream>>>(src, dst, cursor, csr);

    k_l1a<<<NB_SCAN, 256, 0, stream>>>(rp, deg, csr, xn, z);
    k_l1b<<<(N_NODES * 64 + 255) / 256, 256, 0, stream>>>(z, dinv, W1, b1, g);
    k_l2 <<<N_VAR / 4, 256, 0, stream>>>(rp, deg, csr, g, dinv, W2, b2, Wfc, bfc, out);
}